// Round 1
// baseline (1401.363 us; speedup 1.0000x reference)
//
#include <hip/hip_runtime.h>
#include <stdint.h>

typedef unsigned short u16;
typedef __bf16 bf16x8 __attribute__((ext_vector_type(8)));
typedef float f32x4 __attribute__((ext_vector_type(4)));

#define NHEADS 16
#define DKH    128
#define SEQ    2048
#define DMODEL 2048
#define NBATCH 2

typedef const __attribute__((address_space(1))) void* gas1_t;
typedef __attribute__((address_space(3))) void* las3_t;

__device__ __forceinline__ void gload_lds16(const void* g, void* l) {
  __builtin_amdgcn_global_load_lds((gas1_t)(uintptr_t)g,
                                   (las3_t)(uint32_t)(uintptr_t)l, 16, 0, 0);
}

__device__ __forceinline__ u16 f2b(float f) {
  uint32_t u = __builtin_bit_cast(uint32_t, f);
  return (u16)((u + 0x7fffu + ((u >> 16) & 1u)) >> 16);
}

// ---------------- fp32 -> bf16 convert ----------------
__global__ __launch_bounds__(256) void cvt_bf16(const float* __restrict__ in,
                                                u16* __restrict__ out, int n) {
  int i = (blockIdx.x * 256 + threadIdx.x) * 4;
  if (i >= n) return;
  const float4 v = *(const float4*)(in + i);
  uint2 o;
  o.x = (uint32_t)f2b(v.x) | ((uint32_t)f2b(v.y) << 16);
  o.y = (uint32_t)f2b(v.z) | ((uint32_t)f2b(v.w) << 16);
  *(uint2*)(out + i) = o;
}

// ---------------- GEMM: out = x @ w^T, optional fused RoPE ----------------
// ROPE_MODE 1: rope + write [bh][s][d]   (Q, K)
// ROPE_MODE 0: no rope + write [bh][d][s] (V transposed)
template <int ROPE_MODE>
__global__ __launch_bounds__(256, 2) void gemm_qkv(const u16* __restrict__ Abf,
                                                   const u16* __restrict__ Wbf,
                                                   u16* __restrict__ dst) {
  __shared__ u16 As[128 * 32];
  __shared__ u16 Bs[128 * 32];
  const int tid = threadIdx.x;
  const int lane = tid & 63, wid = tid >> 6;
  const int wr = wid >> 1, wc = wid & 1;
  const int m0 = blockIdx.y * 128, n0 = blockIdx.x * 128;
  const int lrow = lane & 15, lko = (lane >> 4) * 8;

  f32x4 acc[4][4] = {};

  for (int k0 = 0; k0 < DMODEL; k0 += 32) {
    __syncthreads();
#pragma unroll
    for (int c = 0; c < 2; ++c) {
      int g = c * 256 + tid;
      int row = g >> 2, ko = (g & 3) * 8;
      gload_lds16(Abf + (size_t)(m0 + row) * DMODEL + k0 + ko,
                  As + (c * 256 + wid * 64) * 8);
      gload_lds16(Wbf + (size_t)(n0 + row) * DMODEL + k0 + ko,
                  Bs + (c * 256 + wid * 64) * 8);
    }
    __syncthreads();
    bf16x8 a[4], b[4];
#pragma unroll
    for (int m = 0; m < 4; ++m)
      a[m] = *(const bf16x8*)(As + (wr * 64 + m * 16 + lrow) * 32 + lko);
#pragma unroll
    for (int n = 0; n < 4; ++n)
      b[n] = *(const bf16x8*)(Bs + (wc * 64 + n * 16 + lrow) * 32 + lko);
#pragma unroll
    for (int m = 0; m < 4; ++m)
#pragma unroll
      for (int n = 0; n < 4; ++n)
        acc[m][n] = __builtin_amdgcn_mfma_f32_16x16x32_bf16(a[m], b[n], acc[m][n], 0, 0, 0);
  }

  const float kLog2Theta = 13.28771237954945f;  // log2(10000)
#pragma unroll
  for (int m = 0; m < 4; ++m) {
    int grow0 = m0 + wr * 64 + m * 16 + ((lane >> 4) << 2);
#pragma unroll
    for (int n = 0; n < 4; ++n) {
      int gcol = n0 + wc * 64 + n * 16 + (lane & 15);
      int h_ = gcol >> 7, d_ = gcol & 127;
      float fr = 0.f;
      if (ROPE_MODE == 1)
        fr = exp2f((float)(d_ >> 1) * (-2.0f / 128.0f) * kLog2Theta);
#pragma unroll
      for (int j = 0; j < 4; ++j) {
        float v = acc[m][n][j];
        int r = grow0 + j;
        int b_ = r >> 11, s_ = r & 2047;
        if (ROPE_MODE == 1) {
          float part = __shfl_xor(v, 1);
          float ang = (float)s_ * fr;
          float sn, cs;
          sincosf(ang, &sn, &cs);
          v = (d_ & 1) ? (part * sn + v * cs) : (v * cs - part * sn);
        }
        int bh = b_ * NHEADS + h_;
        size_t idx;
        if (ROPE_MODE == 0)
          idx = ((size_t)bh * DKH + d_) * SEQ + s_;   // Vt [bh][d][s]
        else
          idx = ((size_t)bh * SEQ + s_) * DKH + d_;   // Q/K [bh][s][d]
        dst[idx] = f2b(v);
      }
    }
  }
}

// ---------------- causal flash attention ----------------
__global__ __launch_bounds__(256, 2) void attn_fwd(const u16* __restrict__ qb,
                                                   const u16* __restrict__ kb,
                                                   const u16* __restrict__ vtb,
                                                   float* __restrict__ out) {
  __shared__ u16 Ks[64 * 128];
  __shared__ u16 Vs[128 * 64];
  __shared__ u16 Ps[4][32 * 64];
  const int tid = threadIdx.x, lane = tid & 63, wid = tid >> 6;
  const int bh = blockIdx.y;
  const int q0 = blockIdx.x * 128;
  const int qw = q0 + wid * 32;
  const int lrow = lane & 15, lgrp = lane >> 4, lko = lgrp * 8;

  bf16x8 qa[2][4];
#pragma unroll
  for (int m = 0; m < 2; ++m)
#pragma unroll
    for (int kd = 0; kd < 4; ++kd)
      qa[m][kd] = *(const bf16x8*)(qb + ((size_t)bh * SEQ + qw + m * 16 + lrow) * DKH +
                                   kd * 32 + lko);

  f32x4 o[2][8] = {};
  float mrun[2][4], lrun[2][4];
#pragma unroll
  for (int m = 0; m < 2; ++m)
#pragma unroll
    for (int j = 0; j < 4; ++j) { mrun[m][j] = -1e30f; lrun[m][j] = 0.f; }

  const float scale = 0.08838834764831845f;  // 1/sqrt(128)
  const int ntiles = (q0 + 128) / 64;

  for (int t = 0; t < ntiles; ++t) {
    const int kv0 = t * 64;
    __syncthreads();  // previous iter's LDS reads finished
#pragma unroll
    for (int c = 0; c < 4; ++c) {
      int g = c * 256 + tid;
      {
        int row = g >> 4, ko = (g & 15) * 8;
        gload_lds16(kb + ((size_t)bh * SEQ + kv0 + row) * DKH + ko,
                    Ks + (c * 256 + wid * 64) * 8);
      }
      {
        int row = g >> 3, so = (g & 7) * 8;
        gload_lds16(vtb + ((size_t)bh * DKH + row) * SEQ + kv0 + so,
                    Vs + (c * 256 + wid * 64) * 8);
      }
    }
    __syncthreads();  // staging complete

    // QK^T
    f32x4 sf[2][4] = {};
#pragma unroll
    for (int kd = 0; kd < 4; ++kd) {
      bf16x8 kf[4];
#pragma unroll
      for (int n = 0; n < 4; ++n)
        kf[n] = *(const bf16x8*)(Ks + (n * 16 + lrow) * DKH + kd * 32 + lko);
#pragma unroll
      for (int m = 0; m < 2; ++m)
#pragma unroll
        for (int n = 0; n < 4; ++n)
          sf[m][n] = __builtin_amdgcn_mfma_f32_16x16x32_bf16(qa[m][kd], kf[n], sf[m][n], 0, 0, 0);
    }

    // online softmax
#pragma unroll
    for (int m = 0; m < 2; ++m) {
      int rbase = qw + m * 16 + lgrp * 4;
#pragma unroll
      for (int j = 0; j < 4; ++j) {
        int r = rbase + j;
        float sv[4];
        float mt = -1e30f;
#pragma unroll
        for (int n = 0; n < 4; ++n) {
          float s = sf[m][n][j] * scale;
          int col = kv0 + n * 16 + (lane & 15);
          if (col > r) s = -1e30f;
          sv[n] = s;
          mt = fmaxf(mt, s);
        }
#pragma unroll
        for (int off = 1; off < 16; off <<= 1) mt = fmaxf(mt, __shfl_xor(mt, off));
        float mnew = fmaxf(mrun[m][j], mt);
        float alpha = __expf(mrun[m][j] - mnew);
        mrun[m][j] = mnew;
        float ps = 0.f;
#pragma unroll
        for (int n = 0; n < 4; ++n) {
          float p = __expf(sv[n] - mnew);
          ps += p;
          sf[m][n][j] = p;
        }
#pragma unroll
        for (int off = 1; off < 16; off <<= 1) ps += __shfl_xor(ps, off);
        lrun[m][j] = lrun[m][j] * alpha + ps;
#pragma unroll
        for (int n8 = 0; n8 < 8; ++n8) o[m][n8][j] *= alpha;
      }
    }

    // write P (bf16) to per-wave LDS
    u16* pw = &Ps[wid][0];
#pragma unroll
    for (int m = 0; m < 2; ++m)
#pragma unroll
      for (int n = 0; n < 4; ++n)
#pragma unroll
        for (int j = 0; j < 4; ++j)
          pw[(m * 16 + lgrp * 4 + j) * 64 + n * 16 + (lane & 15)] = f2b(sf[m][n][j]);
    __syncthreads();  // P visible (block barrier also orders LDS within wave)

    // PV
#pragma unroll
    for (int kk = 0; kk < 2; ++kk) {
      bf16x8 pa[2];
#pragma unroll
      for (int m = 0; m < 2; ++m)
        pa[m] = *(const bf16x8*)(pw + (m * 16 + lrow) * 64 + kk * 32 + lko);
#pragma unroll
      for (int n = 0; n < 8; ++n) {
        bf16x8 vf = *(const bf16x8*)(Vs + (n * 16 + lrow) * 64 + kk * 32 + lko);
#pragma unroll
        for (int m = 0; m < 2; ++m)
          o[m][n] = __builtin_amdgcn_mfma_f32_16x16x32_bf16(pa[m], vf, o[m][n], 0, 0, 0);
      }
    }
  }

  // epilogue
  const int b_ = bh >> 4, h_ = bh & 15;
#pragma unroll
  for (int m = 0; m < 2; ++m)
#pragma unroll
    for (int j = 0; j < 4; ++j) {
      int s_ = qw + m * 16 + lgrp * 4 + j;
      float inv = 1.f / lrun[m][j];
#pragma unroll
      for (int n = 0; n < 8; ++n) {
        int dcol = n * 16 + (lane & 15);
        out[((size_t)b_ * SEQ + s_) * DMODEL + h_ * DKH + dcol] = o[m][n][j] * inv;
      }
    }
}

extern "C" void kernel_launch(void* const* d_in, const int* in_sizes, int n_in,
                              void* d_out, int out_size, void* d_ws, size_t ws_size,
                              hipStream_t stream) {
  const float* x  = (const float*)d_in[0];
  const float* wq = (const float*)d_in[1];
  const float* wk = (const float*)d_in[2];
  const float* wv = (const float*)d_in[3];
  float* out = (float*)d_out;
  char* ws = (char*)d_ws;

  u16* xb  = (u16*)(ws);                       // 4096*2048 bf16 = 16 MB
  u16* wqb = (u16*)(ws + 16777216);            // 8 MB
  u16* wkb = (u16*)(ws + 25165824);            // 8 MB
  u16* wvb = (u16*)(ws + 33554432);            // 8 MB
  u16* qb  = (u16*)(ws + 41943040);            // 16 MB  [bh][s][d]
  u16* kb  = (u16*)(ws + 58720256);            // 16 MB  [bh][s][d]
  u16* vtb = (u16*)(ws + 75497472);            // 16 MB  [bh][d][s]

  cvt_bf16<<<8192, 256, 0, stream>>>(x, xb, NBATCH * SEQ * DMODEL);
  cvt_bf16<<<4096, 256, 0, stream>>>(wq, wqb, DMODEL * DMODEL);
  cvt_bf16<<<4096, 256, 0, stream>>>(wk, wkb, DMODEL * DMODEL);
  cvt_bf16<<<4096, 256, 0, stream>>>(wv, wvb, DMODEL * DMODEL);

  dim3 gg(DMODEL / 128, (NBATCH * SEQ) / 128);
  gemm_qkv<1><<<gg, 256, 0, stream>>>(xb, wqb, qb);
  gemm_qkv<1><<<gg, 256, 0, stream>>>(xb, wkb, kb);
  gemm_qkv<0><<<gg, 256, 0, stream>>>(xb, wvb, vtb);

  attn_fwd<<<dim3(SEQ / 128, NBATCH * NHEADS), 256, 0, stream>>>(qb, kb, vtb, out);
}

// Round 2
// 373.958 us; speedup vs baseline: 3.7474x; 3.7474x over previous
//
#include <hip/hip_runtime.h>
#include <stdint.h>

typedef unsigned short u16;
typedef __bf16 bf16x8 __attribute__((ext_vector_type(8)));
typedef float f32x4 __attribute__((ext_vector_type(4)));

#define NHEADS 16
#define DKH    128
#define SEQ    2048
#define DMODEL 2048
#define NBATCH 2

typedef const __attribute__((address_space(1))) void* gas1_t;
typedef __attribute__((address_space(3))) void* las3_t;

__device__ __forceinline__ void gload_lds16(const void* g, void* l) {
  __builtin_amdgcn_global_load_lds((gas1_t)(uintptr_t)g,
                                   (las3_t)(uint32_t)(uintptr_t)l, 16, 0, 0);
}

__device__ __forceinline__ u16 f2b(float f) {
  uint32_t u = __builtin_bit_cast(uint32_t, f);
  return (u16)((u + 0x7fffu + ((u >> 16) & 1u)) >> 16);
}

// ---------------- fp32 -> bf16 convert ----------------
__global__ __launch_bounds__(256) void cvt_bf16(const float* __restrict__ in,
                                                u16* __restrict__ out, int n) {
  int i = (blockIdx.x * 256 + threadIdx.x) * 4;
  if (i >= n) return;
  const float4 v = *(const float4*)(in + i);
  uint2 o;
  o.x = (uint32_t)f2b(v.x) | ((uint32_t)f2b(v.y) << 16);
  o.y = (uint32_t)f2b(v.z) | ((uint32_t)f2b(v.w) << 16);
  *(uint2*)(out + i) = o;
}

// ---------------- RoPE cos/sin table: tbl[s][d2] = (cos, sin) ----------------
// Keeps ALL transcendentals out of the GEMM (sincosf inlining blew register
// pressure there and spilled the accumulator to scratch: 2.1 GB/dispatch).
__global__ __launch_bounds__(256) void rope_table(float2* __restrict__ tbl) {
  int i = blockIdx.x * 256 + threadIdx.x;  // 2048*64 entries
  int s = i >> 6, d2 = i & 63;
  const float kLog2Theta = 13.28771237954945f;  // log2(10000)
  float inv_freq = exp2f(-(float)d2 * (2.0f / 128.0f) * kLog2Theta);
  float ang = (float)s * inv_freq;
  tbl[i] = make_float2(cosf(ang), sinf(ang));
}

// ---------------- GEMM: out = x @ w^T, optional fused RoPE ----------------
// ROPE_MODE 1: rope + write [bh][s][d]   (Q, K)
// ROPE_MODE 0: no rope + write [bh][d][s] (V transposed)
template <int ROPE_MODE>
__global__ __launch_bounds__(256, 2) void gemm_qkv(const u16* __restrict__ Abf,
                                                   const u16* __restrict__ Wbf,
                                                   const float2* __restrict__ rope,
                                                   u16* __restrict__ dst) {
  __shared__ u16 As[128 * 32];
  __shared__ u16 Bs[128 * 32];
  const int tid = threadIdx.x;
  const int lane = tid & 63, wid = tid >> 6;
  const int wr = wid >> 1, wc = wid & 1;
  const int m0 = blockIdx.y * 128, n0 = blockIdx.x * 128;
  const int lrow = lane & 15, lko = (lane >> 4) * 8;

  f32x4 acc[4][4] = {};

  for (int k0 = 0; k0 < DMODEL; k0 += 32) {
    __syncthreads();
#pragma unroll
    for (int c = 0; c < 2; ++c) {
      int g = c * 256 + tid;
      int row = g >> 2, ko = (g & 3) * 8;
      gload_lds16(Abf + (size_t)(m0 + row) * DMODEL + k0 + ko,
                  As + (c * 256 + wid * 64) * 8);
      gload_lds16(Wbf + (size_t)(n0 + row) * DMODEL + k0 + ko,
                  Bs + (c * 256 + wid * 64) * 8);
    }
    __syncthreads();
    bf16x8 a[4], b[4];
#pragma unroll
    for (int m = 0; m < 4; ++m)
      a[m] = *(const bf16x8*)(As + (wr * 64 + m * 16 + lrow) * 32 + lko);
#pragma unroll
    for (int n = 0; n < 4; ++n)
      b[n] = *(const bf16x8*)(Bs + (wc * 64 + n * 16 + lrow) * 32 + lko);
#pragma unroll
    for (int m = 0; m < 4; ++m)
#pragma unroll
      for (int n = 0; n < 4; ++n)
        acc[m][n] = __builtin_amdgcn_mfma_f32_16x16x32_bf16(a[m], b[n], acc[m][n], 0, 0, 0);
  }

#pragma unroll
  for (int m = 0; m < 4; ++m) {
    int grow0 = m0 + wr * 64 + m * 16 + ((lane >> 4) << 2);
#pragma unroll
    for (int n = 0; n < 4; ++n) {
      int gcol = n0 + wc * 64 + n * 16 + (lane & 15);
      int h_ = gcol >> 7, d_ = gcol & 127;
#pragma unroll
      for (int j = 0; j < 4; ++j) {
        float v = acc[m][n][j];
        int r = grow0 + j;
        int b_ = r >> 11, s_ = r & 2047;
        if (ROPE_MODE == 1) {
          float part = __shfl_xor(v, 1);
          float2 cs2 = rope[s_ * 64 + (d_ >> 1)];
          v = (d_ & 1) ? (part * cs2.y + v * cs2.x) : (v * cs2.x - part * cs2.y);
        }
        int bh = b_ * NHEADS + h_;
        size_t idx;
        if (ROPE_MODE == 0)
          idx = ((size_t)bh * DKH + d_) * SEQ + s_;   // Vt [bh][d][s]
        else
          idx = ((size_t)bh * SEQ + s_) * DKH + d_;   // Q/K [bh][s][d]
        dst[idx] = f2b(v);
      }
    }
  }
}

// ---------------- causal flash attention ----------------
__global__ __launch_bounds__(256, 2) void attn_fwd(const u16* __restrict__ qb,
                                                   const u16* __restrict__ kb,
                                                   const u16* __restrict__ vtb,
                                                   float* __restrict__ out) {
  __shared__ u16 Ks[64 * 128];
  __shared__ u16 Vs[128 * 64];
  __shared__ u16 Ps[4][32 * 64];
  const int tid = threadIdx.x, lane = tid & 63, wid = tid >> 6;
  const int bh = blockIdx.y;
  const int q0 = blockIdx.x * 128;
  const int qw = q0 + wid * 32;
  const int lrow = lane & 15, lgrp = lane >> 4, lko = lgrp * 8;

  bf16x8 qa[2][4];
#pragma unroll
  for (int m = 0; m < 2; ++m)
#pragma unroll
    for (int kd = 0; kd < 4; ++kd)
      qa[m][kd] = *(const bf16x8*)(qb + ((size_t)bh * SEQ + qw + m * 16 + lrow) * DKH +
                                   kd * 32 + lko);

  f32x4 o[2][8] = {};
  float mrun[2][4], lrun[2][4];
#pragma unroll
  for (int m = 0; m < 2; ++m)
#pragma unroll
    for (int j = 0; j < 4; ++j) { mrun[m][j] = -1e30f; lrun[m][j] = 0.f; }

  const float scale = 0.08838834764831845f;  // 1/sqrt(128)
  const int ntiles = (q0 + 128) / 64;

  for (int t = 0; t < ntiles; ++t) {
    const int kv0 = t * 64;
    __syncthreads();  // previous iter's LDS reads finished
#pragma unroll
    for (int c = 0; c < 4; ++c) {
      int g = c * 256 + tid;
      {
        int row = g >> 4, ko = (g & 15) * 8;
        gload_lds16(kb + ((size_t)bh * SEQ + kv0 + row) * DKH + ko,
                    Ks + (c * 256 + wid * 64) * 8);
      }
      {
        int row = g >> 3, so = (g & 7) * 8;
        gload_lds16(vtb + ((size_t)bh * DKH + row) * SEQ + kv0 + so,
                    Vs + (c * 256 + wid * 64) * 8);
      }
    }
    __syncthreads();  // staging complete

    // QK^T
    f32x4 sf[2][4] = {};
#pragma unroll
    for (int kd = 0; kd < 4; ++kd) {
      bf16x8 kf[4];
#pragma unroll
      for (int n = 0; n < 4; ++n)
        kf[n] = *(const bf16x8*)(Ks + (n * 16 + lrow) * DKH + kd * 32 + lko);
#pragma unroll
      for (int m = 0; m < 2; ++m)
#pragma unroll
        for (int n = 0; n < 4; ++n)
          sf[m][n] = __builtin_amdgcn_mfma_f32_16x16x32_bf16(qa[m][kd], kf[n], sf[m][n], 0, 0, 0);
    }

    // online softmax
#pragma unroll
    for (int m = 0; m < 2; ++m) {
      int rbase = qw + m * 16 + lgrp * 4;
#pragma unroll
      for (int j = 0; j < 4; ++j) {
        int r = rbase + j;
        float sv[4];
        float mt = -1e30f;
#pragma unroll
        for (int n = 0; n < 4; ++n) {
          float s = sf[m][n][j] * scale;
          int col = kv0 + n * 16 + (lane & 15);
          if (col > r) s = -1e30f;
          sv[n] = s;
          mt = fmaxf(mt, s);
        }
#pragma unroll
        for (int off = 1; off < 16; off <<= 1) mt = fmaxf(mt, __shfl_xor(mt, off));
        float mnew = fmaxf(mrun[m][j], mt);
        float alpha = __expf(mrun[m][j] - mnew);
        mrun[m][j] = mnew;
        float ps = 0.f;
#pragma unroll
        for (int n = 0; n < 4; ++n) {
          float p = __expf(sv[n] - mnew);
          ps += p;
          sf[m][n][j] = p;
        }
#pragma unroll
        for (int off = 1; off < 16; off <<= 1) ps += __shfl_xor(ps, off);
        lrun[m][j] = lrun[m][j] * alpha + ps;
#pragma unroll
        for (int n8 = 0; n8 < 8; ++n8) o[m][n8][j] *= alpha;
      }
    }

    // write P (bf16) to per-wave LDS
    u16* pw = &Ps[wid][0];
#pragma unroll
    for (int m = 0; m < 2; ++m)
#pragma unroll
      for (int n = 0; n < 4; ++n)
#pragma unroll
        for (int j = 0; j < 4; ++j)
          pw[(m * 16 + lgrp * 4 + j) * 64 + n * 16 + (lane & 15)] = f2b(sf[m][n][j]);
    __syncthreads();  // P visible (block barrier also orders LDS within wave)

    // PV
#pragma unroll
    for (int kk = 0; kk < 2; ++kk) {
      bf16x8 pa[2];
#pragma unroll
      for (int m = 0; m < 2; ++m)
        pa[m] = *(const bf16x8*)(pw + (m * 16 + lrow) * 64 + kk * 32 + lko);
#pragma unroll
      for (int n = 0; n < 8; ++n) {
        bf16x8 vf = *(const bf16x8*)(Vs + (n * 16 + lrow) * 64 + kk * 32 + lko);
#pragma unroll
        for (int m = 0; m < 2; ++m)
          o[m][n] = __builtin_amdgcn_mfma_f32_16x16x32_bf16(pa[m], vf, o[m][n], 0, 0, 0);
      }
    }
  }

  // epilogue
  const int b_ = bh >> 4, h_ = bh & 15;
#pragma unroll
  for (int m = 0; m < 2; ++m)
#pragma unroll
    for (int j = 0; j < 4; ++j) {
      int s_ = qw + m * 16 + lgrp * 4 + j;
      float inv = 1.f / lrun[m][j];
#pragma unroll
      for (int n = 0; n < 8; ++n) {
        int dcol = n * 16 + (lane & 15);
        out[((size_t)b_ * SEQ + s_) * DMODEL + h_ * DKH + dcol] = o[m][n][j] * inv;
      }
    }
}

extern "C" void kernel_launch(void* const* d_in, const int* in_sizes, int n_in,
                              void* d_out, int out_size, void* d_ws, size_t ws_size,
                              hipStream_t stream) {
  const float* x  = (const float*)d_in[0];
  const float* wq = (const float*)d_in[1];
  const float* wk = (const float*)d_in[2];
  const float* wv = (const float*)d_in[3];
  float* out = (float*)d_out;
  char* ws = (char*)d_ws;

  u16* xb  = (u16*)(ws);                       // 4096*2048 bf16 = 16 MB
  u16* wqb = (u16*)(ws + 16777216);            // 8 MB
  u16* wkb = (u16*)(ws + 25165824);            // 8 MB
  u16* wvb = (u16*)(ws + 33554432);            // 8 MB
  u16* qb  = (u16*)(ws + 41943040);            // 16 MB  [bh][s][d]
  u16* kb  = (u16*)(ws + 58720256);            // 16 MB  [bh][s][d]
  u16* vtb = (u16*)(ws + 75497472);            // 16 MB  [bh][d][s]

  // RoPE table lives in the first 1 MB of d_out: it is consumed by the Q/K
  // GEMMs, which complete (stream-ordered) before attn_fwd overwrites all of
  // d_out. Avoids assuming ws_size > 88 MB.
  float2* rope = (float2*)d_out;               // 2048*64*8 = 1 MB

  rope_table<<<512, 256, 0, stream>>>(rope);
  cvt_bf16<<<8192, 256, 0, stream>>>(x, xb, NBATCH * SEQ * DMODEL);
  cvt_bf16<<<4096, 256, 0, stream>>>(wq, wqb, DMODEL * DMODEL);
  cvt_bf16<<<4096, 256, 0, stream>>>(wk, wkb, DMODEL * DMODEL);
  cvt_bf16<<<4096, 256, 0, stream>>>(wv, wvb, DMODEL * DMODEL);

  dim3 gg(DMODEL / 128, (NBATCH * SEQ) / 128);
  gemm_qkv<1><<<gg, 256, 0, stream>>>(xb, wqb, rope, qb);
  gemm_qkv<1><<<gg, 256, 0, stream>>>(xb, wkb, rope, kb);
  gemm_qkv<0><<<gg, 256, 0, stream>>>(xb, wvb, rope, vtb);

  attn_fwd<<<dim3(SEQ / 128, NBATCH * NHEADS), 256, 0, stream>>>(qb, kb, vtb, out);
}

// Round 3
// 284.149 us; speedup vs baseline: 4.9318x; 1.3161x over previous
//
#include <hip/hip_runtime.h>
#include <stdint.h>

typedef unsigned short u16;
typedef __bf16 bf16x8 __attribute__((ext_vector_type(8)));
typedef float f32x4 __attribute__((ext_vector_type(4)));

#define NHEADS 16
#define DKH    128
#define SEQ    2048
#define DMODEL 2048
#define NBATCH 2

typedef const __attribute__((address_space(1))) void* gas1_t;
typedef __attribute__((address_space(3))) void* las3_t;

__device__ __forceinline__ void gload_lds16(const void* g, void* l) {
  __builtin_amdgcn_global_load_lds((gas1_t)(uintptr_t)g,
                                   (las3_t)(uint32_t)(uintptr_t)l, 16, 0, 0);
}

__device__ __forceinline__ u16 f2b(float f) {
  uint32_t u = __builtin_bit_cast(uint32_t, f);
  return (u16)((u + 0x7fffu + ((u >> 16) & 1u)) >> 16);
}

// ---------------- fp32 -> bf16 convert ----------------
__global__ __launch_bounds__(256) void cvt_bf16(const float* __restrict__ in,
                                                u16* __restrict__ out, int n) {
  int i = (blockIdx.x * 256 + threadIdx.x) * 4;
  if (i >= n) return;
  const float4 v = *(const float4*)(in + i);
  uint2 o;
  o.x = (uint32_t)f2b(v.x) | ((uint32_t)f2b(v.y) << 16);
  o.y = (uint32_t)f2b(v.z) | ((uint32_t)f2b(v.w) << 16);
  *(uint2*)(out + i) = o;
}

// ---------------- RoPE cos/sin table ----------------
__global__ __launch_bounds__(256) void rope_table(float2* __restrict__ tbl) {
  int i = blockIdx.x * 256 + threadIdx.x;  // 2048*64 entries
  int s = i >> 6, d2 = i & 63;
  const float kLog2Theta = 13.28771237954945f;  // log2(10000)
  float inv_freq = exp2f(-(float)d2 * (2.0f / 128.0f) * kLog2Theta);
  float ang = (float)s * inv_freq;
  tbl[i] = make_float2(cosf(ang), sinf(ang));
}

// ---------------- GEMM: out = x @ w^T, optional fused RoPE ----------------
template <int ROPE_MODE>
__global__ __launch_bounds__(256, 2) void gemm_qkv(const u16* __restrict__ Abf,
                                                   const u16* __restrict__ Wbf,
                                                   const float2* __restrict__ rope,
                                                   u16* __restrict__ dst) {
  __shared__ u16 As[128 * 32];
  __shared__ u16 Bs[128 * 32];
  const int tid = threadIdx.x;
  const int lane = tid & 63, wid = tid >> 6;
  const int wr = wid >> 1, wc = wid & 1;
  const int m0 = blockIdx.y * 128, n0 = blockIdx.x * 128;
  const int lrow = lane & 15, lko = (lane >> 4) * 8;

  f32x4 acc[4][4] = {};

  for (int k0 = 0; k0 < DMODEL; k0 += 32) {
    __syncthreads();
#pragma unroll
    for (int c = 0; c < 2; ++c) {
      int g = c * 256 + tid;
      int row = g >> 2, ko = (g & 3) * 8;
      gload_lds16(Abf + (size_t)(m0 + row) * DMODEL + k0 + ko,
                  As + (c * 256 + wid * 64) * 8);
      gload_lds16(Wbf + (size_t)(n0 + row) * DMODEL + k0 + ko,
                  Bs + (c * 256 + wid * 64) * 8);
    }
    __syncthreads();
    bf16x8 a[4], b[4];
#pragma unroll
    for (int m = 0; m < 4; ++m)
      a[m] = *(const bf16x8*)(As + (wr * 64 + m * 16 + lrow) * 32 + lko);
#pragma unroll
    for (int n = 0; n < 4; ++n)
      b[n] = *(const bf16x8*)(Bs + (wc * 64 + n * 16 + lrow) * 32 + lko);
#pragma unroll
    for (int m = 0; m < 4; ++m)
#pragma unroll
      for (int n = 0; n < 4; ++n)
        acc[m][n] = __builtin_amdgcn_mfma_f32_16x16x32_bf16(a[m], b[n], acc[m][n], 0, 0, 0);
  }

#pragma unroll
  for (int m = 0; m < 4; ++m) {
    int grow0 = m0 + wr * 64 + m * 16 + ((lane >> 4) << 2);
#pragma unroll
    for (int n = 0; n < 4; ++n) {
      int gcol = n0 + wc * 64 + n * 16 + (lane & 15);
      int h_ = gcol >> 7, d_ = gcol & 127;
#pragma unroll
      for (int j = 0; j < 4; ++j) {
        float v = acc[m][n][j];
        int r = grow0 + j;
        int b_ = r >> 11, s_ = r & 2047;
        if (ROPE_MODE == 1) {
          float part = __shfl_xor(v, 1);
          float2 cs2 = rope[s_ * 64 + (d_ >> 1)];
          v = (d_ & 1) ? (part * cs2.y + v * cs2.x) : (v * cs2.x - part * cs2.y);
        }
        int bh = b_ * NHEADS + h_;
        size_t idx;
        if (ROPE_MODE == 0)
          idx = ((size_t)bh * DKH + d_) * SEQ + s_;   // Vt [bh][d][s]
        else
          idx = ((size_t)bh * SEQ + s_) * DKH + d_;   // Q/K [bh][s][d]
        dst[idx] = f2b(v);
      }
    }
  }
}

// ---------------- causal flash attention (swizzled LDS, balanced) ----------
// Block p handles q-chunks (p, 31-p): (p+1)+(32-p) = 33 KV tiles for EVERY
// block. 4 waves x 16 q-rows. All LDS tiles XOR-swizzled (el ^= (row&7)<<3,
// 16B granularity); staging applies the same XOR to the GLOBAL source so the
// linear global_load_lds write lands swizzled (both-sides rule).
__global__ __launch_bounds__(256, 2) void attn_fwd(const u16* __restrict__ qb,
                                                   const u16* __restrict__ kb,
                                                   const u16* __restrict__ vtb,
                                                   float* __restrict__ out) {
  __shared__ u16 Ks[64 * 128];   // [kv 64][d 128]
  __shared__ u16 Vs[128 * 64];   // [d 128][kv 64]
  __shared__ u16 Ps[4][16 * 64]; // per-wave [q 16][kv 64]
  const int tid = threadIdx.x, lane = tid & 63, wid = tid >> 6;
  const int bh = blockIdx.y;
  const int lrow = lane & 15, lgrp = lane >> 4, lko = lgrp * 8;
  const int swz = (lrow & 7) << 3;  // read-side XOR (elements)

  // staging constants (per thread, fixed across tiles)
  const int krow_l = tid >> 4;               // local K row (step adds c*16)
  const int kcol = ((tid & 15) * 8) ^ ((krow_l & 7) << 3);
  const int vrow_l = tid >> 3;               // local V row (step adds c*32)
  const int vcol = ((tid & 7) * 8) ^ ((vrow_l & 7) << 3);

  const float scale = 0.08838834764831845f;  // 1/sqrt(128)
  const int b_ = bh >> 4, h_ = bh & 15;

#pragma unroll 1
  for (int ci = 0; ci < 2; ++ci) {
    const int chunk = ci ? (31 - (int)blockIdx.x) : (int)blockIdx.x;
    const int qc = chunk * 64;
    const int qrow0 = qc + wid * 16;

    bf16x8 qa[4];
#pragma unroll
    for (int kd = 0; kd < 4; ++kd)
      qa[kd] = *(const bf16x8*)(qb + ((size_t)bh * SEQ + qrow0 + lrow) * DKH +
                                kd * 32 + lko);

    f32x4 o[8] = {};
    float mrun[4], lrun[4];
#pragma unroll
    for (int j = 0; j < 4; ++j) { mrun[j] = -1e30f; lrun[j] = 0.f; }

    const int nt = chunk + 1;
#pragma unroll 1
    for (int t = 0; t < nt; ++t) {
      const int kv0 = t * 64;
      __syncthreads();  // prev tile's LDS reads done / prev chunk done
#pragma unroll
      for (int c = 0; c < 4; ++c) {
        gload_lds16(kb + ((size_t)bh * SEQ + kv0 + c * 16 + krow_l) * DKH + kcol,
                    Ks + (c * 256 + tid) * 8);
        gload_lds16(vtb + ((size_t)bh * DKH + c * 32 + vrow_l) * SEQ + kv0 + vcol,
                    Vs + (c * 256 + tid) * 8);
      }
      __syncthreads();  // staging complete

      // QK^T
      f32x4 sf[4] = {};
#pragma unroll
      for (int kd = 0; kd < 4; ++kd) {
        const int kc = (kd * 32 + lko) ^ swz;
#pragma unroll
        for (int n = 0; n < 4; ++n) {
          bf16x8 kf = *(const bf16x8*)(Ks + (n * 16 + lrow) * 128 + kc);
          sf[n] = __builtin_amdgcn_mfma_f32_16x16x32_bf16(qa[kd], kf, sf[n], 0, 0, 0);
        }
      }

      // online softmax (mask only on the diagonal tile)
      const bool diag = (t == nt - 1);
#pragma unroll
      for (int j = 0; j < 4; ++j) {
        const int r = qrow0 + lgrp * 4 + j;
        float sv[4];
        float mt = -1e30f;
#pragma unroll
        for (int n = 0; n < 4; ++n) {
          float s = sf[n][j] * scale;
          if (diag && (kv0 + n * 16 + lrow > r)) s = -1e30f;
          sv[n] = s;
          mt = fmaxf(mt, s);
        }
#pragma unroll
        for (int off = 1; off < 16; off <<= 1) mt = fmaxf(mt, __shfl_xor(mt, off));
        float mnew = fmaxf(mrun[j], mt);
        float alpha = __expf(mrun[j] - mnew);
        mrun[j] = mnew;
        float ps = 0.f;
#pragma unroll
        for (int n = 0; n < 4; ++n) {
          float p = __expf(sv[n] - mnew);
          ps += p;
          sf[n][j] = p;
        }
#pragma unroll
        for (int off = 1; off < 16; off <<= 1) ps += __shfl_xor(ps, off);
        lrun[j] = lrun[j] * alpha + ps;
#pragma unroll
        for (int n8 = 0; n8 < 8; ++n8) o[n8][j] *= alpha;
      }

      // write P (swizzled, per-wave region; wave-local ds ordering suffices)
      u16* pw = &Ps[wid][0];
#pragma unroll
      for (int n = 0; n < 4; ++n)
#pragma unroll
        for (int j = 0; j < 4; ++j) {
          int prow = lgrp * 4 + j;
          pw[prow * 64 + ((n * 16 + lrow) ^ ((prow & 7) << 3))] = f2b(sf[n][j]);
        }

      // PV
#pragma unroll
      for (int kk = 0; kk < 2; ++kk) {
        const int pc = (kk * 32 + lko) ^ swz;
        bf16x8 pa = *(const bf16x8*)(pw + lrow * 64 + pc);
#pragma unroll
        for (int n = 0; n < 8; ++n) {
          bf16x8 vf = *(const bf16x8*)(Vs + (n * 16 + lrow) * 64 + pc);
          o[n] = __builtin_amdgcn_mfma_f32_16x16x32_bf16(pa, vf, o[n], 0, 0, 0);
        }
      }
    }

    // epilogue for this chunk
#pragma unroll
    for (int j = 0; j < 4; ++j) {
      int s_ = qrow0 + lgrp * 4 + j;
      float inv = 1.f / lrun[j];
#pragma unroll
      for (int n = 0; n < 8; ++n) {
        int dcol = n * 16 + lrow;
        out[((size_t)b_ * SEQ + s_) * DMODEL + h_ * DKH + dcol] = o[n][j] * inv;
      }
    }
  }
}

extern "C" void kernel_launch(void* const* d_in, const int* in_sizes, int n_in,
                              void* d_out, int out_size, void* d_ws, size_t ws_size,
                              hipStream_t stream) {
  const float* x  = (const float*)d_in[0];
  const float* wq = (const float*)d_in[1];
  const float* wk = (const float*)d_in[2];
  const float* wv = (const float*)d_in[3];
  float* out = (float*)d_out;
  char* ws = (char*)d_ws;

  u16* xb  = (u16*)(ws);                       // 16 MB
  u16* wqb = (u16*)(ws + 16777216);            // 8 MB
  u16* wkb = (u16*)(ws + 25165824);            // 8 MB
  u16* wvb = (u16*)(ws + 33554432);            // 8 MB
  u16* qb  = (u16*)(ws + 41943040);            // 16 MB  [bh][s][d]
  u16* kb  = (u16*)(ws + 58720256);            // 16 MB  [bh][s][d]
  u16* vtb = (u16*)(ws + 75497472);            // 16 MB  [bh][d][s]

  // RoPE table in the first 1 MB of d_out (consumed before attn overwrites).
  float2* rope = (float2*)d_out;               // 2048*64*8 = 1 MB

  rope_table<<<512, 256, 0, stream>>>(rope);
  cvt_bf16<<<8192, 256, 0, stream>>>(x, xb, NBATCH * SEQ * DMODEL);
  cvt_bf16<<<4096, 256, 0, stream>>>(wq, wqb, DMODEL * DMODEL);
  cvt_bf16<<<4096, 256, 0, stream>>>(wk, wkb, DMODEL * DMODEL);
  cvt_bf16<<<4096, 256, 0, stream>>>(wv, wvb, DMODEL * DMODEL);

  dim3 gg(DMODEL / 128, (NBATCH * SEQ) / 128);
  gemm_qkv<1><<<gg, 256, 0, stream>>>(xb, wqb, rope, qb);
  gemm_qkv<1><<<gg, 256, 0, stream>>>(xb, wkb, rope, kb);
  gemm_qkv<0><<<gg, 256, 0, stream>>>(xb, wvb, rope, vtb);

  attn_fwd<<<dim3(16, NBATCH * NHEADS), 256, 0, stream>>>(qb, kb, vtb, out);
}

// Round 4
// 239.584 us; speedup vs baseline: 5.8492x; 1.1860x over previous
//
#include <hip/hip_runtime.h>
#include <stdint.h>

typedef unsigned short u16;
typedef __bf16 bf16x8 __attribute__((ext_vector_type(8)));
typedef float f32x4 __attribute__((ext_vector_type(4)));

#define NHEADS 16
#define DKH    128
#define SEQ    2048
#define DMODEL 2048
#define NBATCH 2

typedef const __attribute__((address_space(1))) void* gas1_t;
typedef __attribute__((address_space(3))) void* las3_t;

__device__ __forceinline__ void gload_lds16(const void* g, void* l) {
  __builtin_amdgcn_global_load_lds((gas1_t)(uintptr_t)g,
                                   (las3_t)(uint32_t)(uintptr_t)l, 16, 0, 0);
}

__device__ __forceinline__ u16 f2b(float f) {
  uint32_t u = __builtin_bit_cast(uint32_t, f);
  return (u16)((u + 0x7fffu + ((u >> 16) & 1u)) >> 16);
}

// ---------------- fp32 -> bf16 convert ----------------
__global__ __launch_bounds__(256) void cvt_bf16(const float* __restrict__ in,
                                                u16* __restrict__ out, int n) {
  int i = (blockIdx.x * 256 + threadIdx.x) * 4;
  if (i >= n) return;
  const float4 v = *(const float4*)(in + i);
  uint2 o;
  o.x = (uint32_t)f2b(v.x) | ((uint32_t)f2b(v.y) << 16);
  o.y = (uint32_t)f2b(v.z) | ((uint32_t)f2b(v.w) << 16);
  *(uint2*)(out + i) = o;
}

// ---------------- RoPE cos/sin table ----------------
__global__ __launch_bounds__(256) void rope_table(float2* __restrict__ tbl) {
  int i = blockIdx.x * 256 + threadIdx.x;  // 2048*64 entries
  int s = i >> 6, d2 = i & 63;
  const float kLog2Theta = 13.28771237954945f;  // log2(10000)
  float inv_freq = exp2f(-(float)d2 * (2.0f / 128.0f) * kLog2Theta);
  float ang = (float)s * inv_freq;
  tbl[i] = make_float2(cosf(ang), sinf(ang));
}

// ---------------- GEMM: out = x @ w^T, BK=64, swizzled LDS ----------------
// LDS tiles [128][64] bf16, 16B-chunk XOR swizzle: chunk ^= (row&7).
// Swizzle applied on the GLOBAL source address (global_load_lds writes
// linearly) and on the LDS read address (both-sides rule).
template <int ROPE_MODE>
__global__ __launch_bounds__(256, 2) void gemm_qkv(const u16* __restrict__ Abf,
                                                   const u16* __restrict__ Wbf,
                                                   const float2* __restrict__ rope,
                                                   u16* __restrict__ dst) {
  __shared__ u16 As[128 * 64];
  __shared__ u16 Bs[128 * 64];
  const int tid = threadIdx.x;
  const int lane = tid & 63, wid = tid >> 6;
  const int wr = wid >> 1, wc = wid & 1;
  const int m0 = blockIdx.y * 128, n0 = blockIdx.x * 128;
  const int lrow = lane & 15, lko = (lane >> 4) * 8;
  const int rswz = (lrow & 7) << 3;  // read-side XOR (elements)

  // staging: per c (0..3): row = c*32 + (tid>>3); since c*32 % 8 == 0 the
  // XOR is constant per thread: srccol = (tid&7)*8 ^ ((tid>>3)&7)<<3
  const int srow = tid >> 3;
  const int scol = ((tid & 7) * 8) ^ (((tid >> 3) & 7) << 3);

  f32x4 acc[4][4] = {};

  for (int k0 = 0; k0 < DMODEL; k0 += 64) {
    __syncthreads();
#pragma unroll
    for (int c = 0; c < 4; ++c) {
      gload_lds16(Abf + (size_t)(m0 + c * 32 + srow) * DMODEL + k0 + scol,
                  As + (c * 256 + tid) * 8);
      gload_lds16(Wbf + (size_t)(n0 + c * 32 + srow) * DMODEL + k0 + scol,
                  Bs + (c * 256 + tid) * 8);
    }
    __syncthreads();
#pragma unroll
    for (int kk = 0; kk < 2; ++kk) {
      const int rc = (kk * 32 + lko) ^ rswz;
      bf16x8 a[4], b[4];
#pragma unroll
      for (int m = 0; m < 4; ++m)
        a[m] = *(const bf16x8*)(As + (wr * 64 + m * 16 + lrow) * 64 + rc);
#pragma unroll
      for (int n = 0; n < 4; ++n)
        b[n] = *(const bf16x8*)(Bs + (wc * 64 + n * 16 + lrow) * 64 + rc);
#pragma unroll
      for (int m = 0; m < 4; ++m)
#pragma unroll
        for (int n = 0; n < 4; ++n)
          acc[m][n] = __builtin_amdgcn_mfma_f32_16x16x32_bf16(a[m], b[n], acc[m][n], 0, 0, 0);
    }
  }

#pragma unroll
  for (int m = 0; m < 4; ++m) {
    int grow0 = m0 + wr * 64 + m * 16 + ((lane >> 4) << 2);
#pragma unroll
    for (int n = 0; n < 4; ++n) {
      int gcol = n0 + wc * 64 + n * 16 + (lane & 15);
      int h_ = gcol >> 7, d_ = gcol & 127;
#pragma unroll
      for (int j = 0; j < 4; ++j) {
        float v = acc[m][n][j];
        int r = grow0 + j;
        int b_ = r >> 11, s_ = r & 2047;
        if (ROPE_MODE == 1) {
          float part = __shfl_xor(v, 1);
          float2 cs2 = rope[s_ * 64 + (d_ >> 1)];
          v = (d_ & 1) ? (part * cs2.y + v * cs2.x) : (v * cs2.x - part * cs2.y);
        }
        int bh = b_ * NHEADS + h_;
        size_t idx;
        if (ROPE_MODE == 0)
          idx = ((size_t)bh * DKH + d_) * SEQ + s_;   // Vt [bh][d][s]
        else
          idx = ((size_t)bh * SEQ + s_) * DKH + d_;   // Q/K [bh][s][d]
        dst[idx] = f2b(v);
      }
    }
  }
}

// ---------------- causal flash attention ----------------
// XCD-affine mapping: all 16 chunk-pair blocks of one bh land on one XCD
// (blk%8 = XCD round-robin), so K/V (1 MB/bh, 4 bh/XCD) stay L2-resident.
// Block handles q-chunks (p, 31-p) => 33 KV tiles for every block.
__global__ __launch_bounds__(256, 2) void attn_fwd(const u16* __restrict__ qb,
                                                   const u16* __restrict__ kb,
                                                   const u16* __restrict__ vtb,
                                                   float* __restrict__ out) {
  __shared__ u16 Ks[64 * 128];   // [kv 64][d 128]
  __shared__ u16 Vs[128 * 64];   // [d 128][kv 64]
  __shared__ u16 Ps[4][16 * 64]; // per-wave [q 16][kv 64]
  const int tid = threadIdx.x, lane = tid & 63, wid = tid >> 6;
  const int blk = blockIdx.x;
  const int xcd = blk & 7, slot = blk >> 3;
  const int bh = (slot >> 4) * 8 + xcd;
  const int pair = slot & 15;
  const int lrow = lane & 15, lgrp = lane >> 4, lko = lgrp * 8;
  const int swz = (lrow & 7) << 3;  // read-side XOR (elements)

  const int krow_l = tid >> 4;
  const int kcol = ((tid & 15) * 8) ^ ((krow_l & 7) << 3);
  const int vrow_l = tid >> 3;
  const int vcol = ((tid & 7) * 8) ^ ((vrow_l & 7) << 3);

  const float scale = 0.08838834764831845f;  // 1/sqrt(128)
  const int b_ = bh >> 4, h_ = bh & 15;

#pragma unroll 1
  for (int ci = 0; ci < 2; ++ci) {
    const int chunk = ci ? (31 - pair) : pair;
    const int qrow0 = chunk * 64 + wid * 16;

    bf16x8 qa[4];
#pragma unroll
    for (int kd = 0; kd < 4; ++kd)
      qa[kd] = *(const bf16x8*)(qb + ((size_t)bh * SEQ + qrow0 + lrow) * DKH +
                                kd * 32 + lko);

    f32x4 o[8] = {};
    float mrun[4], lrun[4];
#pragma unroll
    for (int j = 0; j < 4; ++j) { mrun[j] = -1e30f; lrun[j] = 0.f; }

    const int nt = chunk + 1;
#pragma unroll 1
    for (int t = 0; t < nt; ++t) {
      const int kv0 = t * 64;
      __syncthreads();  // prev tile's LDS reads done
#pragma unroll
      for (int c = 0; c < 4; ++c) {
        gload_lds16(kb + ((size_t)bh * SEQ + kv0 + c * 16 + krow_l) * DKH + kcol,
                    Ks + (c * 256 + tid) * 8);
        gload_lds16(vtb + ((size_t)bh * DKH + c * 32 + vrow_l) * SEQ + kv0 + vcol,
                    Vs + (c * 256 + tid) * 8);
      }
      __syncthreads();  // staging complete

      // QK^T
      f32x4 sf[4] = {};
#pragma unroll
      for (int kd = 0; kd < 4; ++kd) {
        const int kc = (kd * 32 + lko) ^ swz;
#pragma unroll
        for (int n = 0; n < 4; ++n) {
          bf16x8 kf = *(const bf16x8*)(Ks + (n * 16 + lrow) * 128 + kc);
          sf[n] = __builtin_amdgcn_mfma_f32_16x16x32_bf16(qa[kd], kf, sf[n], 0, 0, 0);
        }
      }

      // online softmax with deferred rescale (THR=8)
      const bool diag = (t == nt - 1);
      float mt[4];
      float sv[4][4];
#pragma unroll
      for (int j = 0; j < 4; ++j) {
        const int r = qrow0 + lgrp * 4 + j;
        float m_ = -1e30f;
#pragma unroll
        for (int n = 0; n < 4; ++n) {
          float s = sf[n][j] * scale;
          if (diag && (kv0 + n * 16 + lrow > r)) s = -1e30f;
          sv[n][j] = s;
          m_ = fmaxf(m_, s);
        }
#pragma unroll
        for (int off = 1; off < 16; off <<= 1) m_ = fmaxf(m_, __shfl_xor(m_, off));
        mt[j] = m_;
      }
      int need = 0;
#pragma unroll
      for (int j = 0; j < 4; ++j) need |= (mt[j] > mrun[j] + 8.0f) ? 1 : 0;
      if (__any(need)) {
#pragma unroll
        for (int j = 0; j < 4; ++j) {
          float mnew = fmaxf(mrun[j], mt[j]);
          float alpha = __expf(mrun[j] - mnew);
          mrun[j] = mnew;
          lrun[j] *= alpha;
#pragma unroll
          for (int n8 = 0; n8 < 8; ++n8) o[n8][j] *= alpha;
        }
      }
#pragma unroll
      for (int j = 0; j < 4; ++j) {
        float ps = 0.f;
#pragma unroll
        for (int n = 0; n < 4; ++n) {
          float p = __expf(sv[n][j] - mrun[j]);
          ps += p;
          sf[n][j] = p;
        }
#pragma unroll
        for (int off = 1; off < 16; off <<= 1) ps += __shfl_xor(ps, off);
        lrun[j] += ps;
      }

      // write P (swizzled, per-wave region)
      u16* pw = &Ps[wid][0];
#pragma unroll
      for (int n = 0; n < 4; ++n)
#pragma unroll
        for (int j = 0; j < 4; ++j) {
          int prow = lgrp * 4 + j;
          pw[prow * 64 + ((n * 16 + lrow) ^ ((prow & 7) << 3))] = f2b(sf[n][j]);
        }

      // PV
#pragma unroll
      for (int kk = 0; kk < 2; ++kk) {
        const int pc = (kk * 32 + lko) ^ swz;
        bf16x8 pa = *(const bf16x8*)(pw + lrow * 64 + pc);
#pragma unroll
        for (int n = 0; n < 8; ++n) {
          bf16x8 vf = *(const bf16x8*)(Vs + (n * 16 + lrow) * 64 + pc);
          o[n] = __builtin_amdgcn_mfma_f32_16x16x32_bf16(pa, vf, o[n], 0, 0, 0);
        }
      }
    }

    // epilogue for this chunk
#pragma unroll
    for (int j = 0; j < 4; ++j) {
      int s_ = qrow0 + lgrp * 4 + j;
      float inv = 1.f / lrun[j];
#pragma unroll
      for (int n = 0; n < 8; ++n) {
        int dcol = n * 16 + lrow;
        out[((size_t)b_ * SEQ + s_) * DMODEL + h_ * DKH + dcol] = o[n][j] * inv;
      }
    }
  }
}

extern "C" void kernel_launch(void* const* d_in, const int* in_sizes, int n_in,
                              void* d_out, int out_size, void* d_ws, size_t ws_size,
                              hipStream_t stream) {
  const float* x  = (const float*)d_in[0];
  const float* wq = (const float*)d_in[1];
  const float* wk = (const float*)d_in[2];
  const float* wv = (const float*)d_in[3];
  float* out = (float*)d_out;
  char* ws = (char*)d_ws;

  u16* xb  = (u16*)(ws);                       // 16 MB
  u16* wqb = (u16*)(ws + 16777216);            // 8 MB
  u16* wkb = (u16*)(ws + 25165824);            // 8 MB
  u16* wvb = (u16*)(ws + 33554432);            // 8 MB
  u16* qb  = (u16*)(ws + 41943040);            // 16 MB  [bh][s][d]
  u16* kb  = (u16*)(ws + 58720256);            // 16 MB  [bh][s][d]
  u16* vtb = (u16*)(ws + 75497472);            // 16 MB  [bh][d][s]

  // RoPE table in the first 1 MB of d_out (consumed before attn overwrites).
  float2* rope = (float2*)d_out;               // 2048*64*8 = 1 MB

  rope_table<<<512, 256, 0, stream>>>(rope);
  cvt_bf16<<<8192, 256, 0, stream>>>(x, xb, NBATCH * SEQ * DMODEL);
  cvt_bf16<<<4096, 256, 0, stream>>>(wq, wqb, DMODEL * DMODEL);
  cvt_bf16<<<4096, 256, 0, stream>>>(wk, wkb, DMODEL * DMODEL);
  cvt_bf16<<<4096, 256, 0, stream>>>(wv, wvb, DMODEL * DMODEL);

  dim3 gg(DMODEL / 128, (NBATCH * SEQ) / 128);
  gemm_qkv<1><<<gg, 256, 0, stream>>>(xb, wqb, rope, qb);
  gemm_qkv<1><<<gg, 256, 0, stream>>>(xb, wkb, rope, kb);
  gemm_qkv<0><<<gg, 256, 0, stream>>>(xb, wvb, rope, vtb);

  attn_fwd<<<dim3(512), 256, 0, stream>>>(qb, kb, vtb, out);
}